// Round 2
// baseline (2884.230 us; speedup 1.0000x reference)
//
#include <hip/hip_runtime.h>
#include <math.h>

#define BN_EPS 1e-3f

typedef __attribute__((ext_vector_type(8))) unsigned short ushort8v;

__device__ __forceinline__ float4 f4load(const float* p) {
    return *reinterpret_cast<const float4*>(p);
}
__device__ __forceinline__ float bf2f(unsigned short u) {
    union { unsigned int i; float f; } w; w.i = ((unsigned int)u) << 16; return w.f;
}
__device__ __forceinline__ unsigned short f2bf(float f) {
    union { float fv; unsigned int i; } w; w.fv = f;
    unsigned int lsb = (w.i >> 16) & 1u;
    w.i += 0x7fffu + lsb;             // round-to-nearest-even
    return (unsigned short)(w.i >> 16);
}

// ---------------- Block 0: cin=1, cout=32, 96^3 -> 48^3 (fp32 in, bf16 out)
__global__ __launch_bounds__(256) void conv0_kernel(
    const float* __restrict__ x, const float* __restrict__ k,
    const float* __restrict__ b, const float* __restrict__ g,
    const float* __restrict__ be, const float* __restrict__ m,
    const float* __restrict__ v, unsigned short* __restrict__ y)
{
    int tid = blockIdx.x * blockDim.x + threadIdx.x;
    int co4 = tid & 7;            // 32/4 = 8 channel-groups
    int sp  = tid >> 3;
    int ow = sp % 48; sp /= 48;
    int oh = sp % 48; sp /= 48;
    int od = sp % 48; int n = sp / 48;
    if (n >= 16) return;

    const int id0 = od * 2, ih0 = oh * 2, iw0 = ow * 2;
    float4 acc = make_float4(0.f, 0.f, 0.f, 0.f);
    const float* xb = x + ((size_t)(n * 96 + id0) * 96 + ih0) * 96 + iw0;

    for (int kd = 0; kd < 3 && id0 + kd < 96; ++kd)
        for (int kh = 0; kh < 3 && ih0 + kh < 96; ++kh)
            for (int kw = 0; kw < 3 && iw0 + kw < 96; ++kw) {
                float xv = xb[(kd * 96 + kh) * 96 + kw];
                float4 wv = f4load(k + ((kd * 3 + kh) * 3 + kw) * 32 + co4 * 4);
                acc.x += xv * wv.x; acc.y += xv * wv.y;
                acc.z += xv * wv.z; acc.w += xv * wv.w;
            }

    int c0 = co4 * 4;
    float4 gv = f4load(g + c0), bev = f4load(be + c0);
    float4 mv = f4load(m + c0), vv = f4load(v + c0), bv = f4load(b + c0);
    float s;
    ushort4 out;
    s = gv.x * rsqrtf(vv.x + BN_EPS); out.x = f2bf(fmaxf((acc.x + bv.x - mv.x) * s + bev.x, 0.f));
    s = gv.y * rsqrtf(vv.y + BN_EPS); out.y = f2bf(fmaxf((acc.y + bv.y - mv.y) * s + bev.y, 0.f));
    s = gv.z * rsqrtf(vv.z + BN_EPS); out.z = f2bf(fmaxf((acc.z + bv.z - mv.z) * s + bev.z, 0.f));
    s = gv.w * rsqrtf(vv.w + BN_EPS); out.w = f2bf(fmaxf((acc.w + bv.w - mv.w) * s + bev.w, 0.f));

    unsigned short* yp = y + (((size_t)(n * 48 + od) * 48 + oh) * 48 + ow) * 32 + c0;
    *reinterpret_cast<ushort4*>(yp) = out;
}

// ---------------- Generic block: CIN -> COUT, INS^3 -> OUTS^3, stride 2 ----
// bf16 activations in/out, fp32 weights + accumulation.
template<int CIN, int COUT, int INS, int OUTS>
__global__ __launch_bounds__(256) void conv_kernel(
    const unsigned short* __restrict__ x, const float* __restrict__ k,
    const float* __restrict__ b, const float* __restrict__ g,
    const float* __restrict__ be, const float* __restrict__ m,
    const float* __restrict__ v, unsigned short* __restrict__ y)
{
    constexpr int NCO4 = COUT / 4;
    int tid = blockIdx.x * blockDim.x + threadIdx.x;
    int co4 = tid & (NCO4 - 1);
    int sp  = tid / NCO4;
    int ow = sp % OUTS; sp /= OUTS;
    int oh = sp % OUTS; sp /= OUTS;
    int od = sp % OUTS; int n = sp / OUTS;
    if (n >= 16) return;

    const int id0 = od * 2, ih0 = oh * 2, iw0 = ow * 2;
    float4 acc = make_float4(0.f, 0.f, 0.f, 0.f);

    for (int kd = 0; kd < 3 && id0 + kd < INS; ++kd)
        for (int kh = 0; kh < 3 && ih0 + kh < INS; ++kh)
            for (int kw = 0; kw < 3 && iw0 + kw < INS; ++kw) {
                const unsigned short* xp = x + (((size_t)(n * INS + id0 + kd) * INS + ih0 + kh) * INS + iw0 + kw) * CIN;
                const float* wp = k + (size_t)((kd * 3 + kh) * 3 + kw) * CIN * COUT + co4 * 4;
                #pragma unroll 4
                for (int ci = 0; ci < CIN; ci += 8) {
                    ushort8v xv8 = *reinterpret_cast<const ushort8v*>(xp + ci);
                    #pragma unroll
                    for (int j = 0; j < 8; ++j) {
                        float xv = bf2f(xv8[j]);
                        float4 wv = f4load(wp + (size_t)(ci + j) * COUT);
                        acc.x += xv * wv.x; acc.y += xv * wv.y;
                        acc.z += xv * wv.z; acc.w += xv * wv.w;
                    }
                }
            }

    int c0 = co4 * 4;
    float4 gv = f4load(g + c0), bev = f4load(be + c0);
    float4 mv = f4load(m + c0), vv = f4load(v + c0), bv = f4load(b + c0);
    float s;
    ushort4 out;
    s = gv.x * rsqrtf(vv.x + BN_EPS); out.x = f2bf(fmaxf((acc.x + bv.x - mv.x) * s + bev.x, 0.f));
    s = gv.y * rsqrtf(vv.y + BN_EPS); out.y = f2bf(fmaxf((acc.y + bv.y - mv.y) * s + bev.y, 0.f));
    s = gv.z * rsqrtf(vv.z + BN_EPS); out.z = f2bf(fmaxf((acc.z + bv.z - mv.z) * s + bev.z, 0.f));
    s = gv.w * rsqrtf(vv.w + BN_EPS); out.w = f2bf(fmaxf((acc.w + bv.w - mv.w) * s + bev.w, 0.f));

    unsigned short* yp = y + (((size_t)(n * OUTS + od) * OUTS + oh) * OUTS + ow) * COUT + c0;
    *reinterpret_cast<ushort4*>(yp) = out;
}

// ---------------- Head: mean pool + 1x1 conv + BN/ReLU + 1x1 conv + top2 softmax
__global__ __launch_bounds__(256) void head_kernel(
    const unsigned short* __restrict__ x4,   // (16, 6,6,6, 256) bf16
    const float* __restrict__ w1k, const float* __restrict__ w1b,
    const float* __restrict__ wg,  const float* __restrict__ wbe,
    const float* __restrict__ wm,  const float* __restrict__ wv,
    const float* __restrict__ w2k, const float* __restrict__ w2b,
    float* __restrict__ out)
{
    __shared__ float h[256];
    __shared__ float r[256];
    __shared__ float logits[8];

    int n = blockIdx.x;
    int c = threadIdx.x;

    // mean over 216 spatial positions
    float s = 0.f;
    const unsigned short* xp = x4 + (size_t)n * 216 * 256 + c;
    for (int i = 0; i < 216; ++i) s += bf2f(xp[(size_t)i * 256]);
    h[c] = s * (1.0f / 216.0f);
    __syncthreads();

    // w1 (256x256) + BN + ReLU
    float a = w1b[c];
    #pragma unroll 4
    for (int ci = 0; ci < 256; ++ci) a += h[ci] * w1k[ci * 256 + c];
    float sc = wg[c] * rsqrtf(wv[c] + BN_EPS);
    a = (a - wm[c]) * sc + wbe[c];
    r[c] = fmaxf(a, 0.f);
    __syncthreads();

    // w2 (256x8)
    if (c < 8) {
        float a2 = w2b[c];
        for (int ci = 0; ci < 256; ++ci) a2 += r[ci] * w2k[ci * 8 + c];
        logits[c] = a2;
    }
    __syncthreads();

    // top-2 threshold + masked softmax (8 elements, serial on thread 0)
    if (c == 0) {
        float m1 = -INFINITY, m2 = -INFINITY;
        for (int e = 0; e < 8; ++e) {
            float val = logits[e];
            if (val > m1) { m2 = m1; m1 = val; }
            else if (val > m2) { m2 = val; }
        }
        float thr = m2;
        float ex[8]; float sum = 0.f;
        for (int e = 0; e < 8; ++e) {
            float val = (logits[e] >= thr) ? logits[e] : -INFINITY;
            ex[e] = expf(val - m1);
            sum += ex[e];
        }
        float inv = 1.0f / sum;
        for (int e = 0; e < 8; ++e) out[n * 8 + e] = ex[e] * inv;
    }
}

extern "C" void kernel_launch(void* const* d_in, const int* in_sizes, int n_in,
                              void* d_out, int out_size, void* d_ws, size_t ws_size,
                              hipStream_t stream) {
    const float* x   = (const float*)d_in[0];
    const float* k0  = (const float*)d_in[1];
    const float* b0  = (const float*)d_in[2];
    const float* g0  = (const float*)d_in[3];
    const float* be0 = (const float*)d_in[4];
    const float* m0  = (const float*)d_in[5];
    const float* v0  = (const float*)d_in[6];
    const float* k1  = (const float*)d_in[7];
    const float* b1  = (const float*)d_in[8];
    const float* g1  = (const float*)d_in[9];
    const float* be1 = (const float*)d_in[10];
    const float* m1  = (const float*)d_in[11];
    const float* v1  = (const float*)d_in[12];
    const float* k2  = (const float*)d_in[13];
    const float* b2  = (const float*)d_in[14];
    const float* g2  = (const float*)d_in[15];
    const float* be2 = (const float*)d_in[16];
    const float* m2  = (const float*)d_in[17];
    const float* v2  = (const float*)d_in[18];
    const float* k3  = (const float*)d_in[19];
    const float* b3  = (const float*)d_in[20];
    const float* g3  = (const float*)d_in[21];
    const float* be3 = (const float*)d_in[22];
    const float* m3  = (const float*)d_in[23];
    const float* v3  = (const float*)d_in[24];
    const float* w1k = (const float*)d_in[25];
    const float* w1b = (const float*)d_in[26];
    const float* wg  = (const float*)d_in[27];
    const float* wbe = (const float*)d_in[28];
    const float* wm  = (const float*)d_in[29];
    const float* wv  = (const float*)d_in[30];
    const float* w2k = (const float*)d_in[31];
    const float* w2b = (const float*)d_in[32];

    // workspace layout (bf16 elements):
    //   x1: 16*48^3*32  = 56,623,104  (113.2 MB)
    //   x2: 16*24^3*64  = 14,155,776  ( 28.3 MB)
    //   x3: 16*12^3*128 =  3,538,944  (  7.1 MB)
    //   x4: 16* 6^3*256 =    884,736  (  1.8 MB)
    // total ~150.4 MB
    unsigned short* x1 = (unsigned short*)d_ws;
    unsigned short* x2 = x1 + 56623104;
    unsigned short* x3 = x2 + 14155776;
    unsigned short* x4 = x3 + 3538944;

    conv0_kernel<<<55296, 256, 0, stream>>>(x, k0, b0, g0, be0, m0, v0, x1);
    conv_kernel<32, 64, 48, 24><<<13824, 256, 0, stream>>>(x1, k1, b1, g1, be1, m1, v1, x2);
    conv_kernel<64, 128, 24, 12><<<3456, 256, 0, stream>>>(x2, k2, b2, g2, be2, m2, v2, x3);
    conv_kernel<128, 256, 12, 6><<<864, 256, 0, stream>>>(x3, k3, b3, g3, be3, m3, v3, x4);
    head_kernel<<<16, 256, 0, stream>>>(x4, w1k, w1b, wg, wbe, wm, wv, w2k, w2b, (float*)d_out);
}

// Round 3
// 696.365 us; speedup vs baseline: 4.1418x; 4.1418x over previous
//
#include <hip/hip_runtime.h>
#include <math.h>

#define BN_EPS 1e-3f

typedef __attribute__((ext_vector_type(8))) unsigned short ushort8v;
typedef __attribute__((ext_vector_type(8))) short short8v;
typedef __attribute__((ext_vector_type(4))) float f32x4;

__device__ __forceinline__ float4 f4load(const float* p) {
    return *reinterpret_cast<const float4*>(p);
}
__device__ __forceinline__ float bf2f(unsigned short u) {
    union { unsigned int i; float f; } w; w.i = ((unsigned int)u) << 16; return w.f;
}
__device__ __forceinline__ unsigned short f2bf(float f) {
    union { float fv; unsigned int i; } w; w.fv = f;
    unsigned int lsb = (w.i >> 16) & 1u;
    w.i += 0x7fffu + lsb;             // round-to-nearest-even
    return (unsigned short)(w.i >> 16);
}

// ---------------- Weight prep: k[tap][cin][cout] f32 -> Wt[tap][cout][cin] bf16
template<int CIN, int COUT>
__global__ __launch_bounds__(256) void wprep_kernel(
    const float* __restrict__ k, unsigned short* __restrict__ wt)
{
    int idx = blockIdx.x * 256 + threadIdx.x;
    constexpr int CI8 = CIN / 8;
    if (idx >= 27 * COUT * CI8) return;
    int ci0 = (idx % CI8) * 8;
    int c   = (idx / CI8) % COUT;
    int t   = idx / (CI8 * COUT);
    ushort8v o;
    #pragma unroll
    for (int j = 0; j < 8; ++j)
        o[j] = f2bf(k[(size_t)(t * CIN + ci0 + j) * COUT + c]);
    *reinterpret_cast<ushort8v*>(wt + ((size_t)t * COUT + c) * CIN + ci0) = o;
}

// ---------------- Block 0: cin=1, cout=32, 96^3 -> 48^3 (fp32 in, bf16 out)
__global__ __launch_bounds__(256) void conv0_kernel(
    const float* __restrict__ x, const float* __restrict__ k,
    const float* __restrict__ b, const float* __restrict__ g,
    const float* __restrict__ be, const float* __restrict__ m,
    const float* __restrict__ v, unsigned short* __restrict__ y)
{
    int tid = blockIdx.x * blockDim.x + threadIdx.x;
    int co4 = tid & 7;
    int sp  = tid >> 3;
    int ow = sp % 48; sp /= 48;
    int oh = sp % 48; sp /= 48;
    int od = sp % 48; int n = sp / 48;
    if (n >= 16) return;

    const int id0 = od * 2, ih0 = oh * 2, iw0 = ow * 2;
    float4 acc = make_float4(0.f, 0.f, 0.f, 0.f);
    const float* xb = x + ((size_t)(n * 96 + id0) * 96 + ih0) * 96 + iw0;

    for (int kd = 0; kd < 3 && id0 + kd < 96; ++kd)
        for (int kh = 0; kh < 3 && ih0 + kh < 96; ++kh)
            for (int kw = 0; kw < 3 && iw0 + kw < 96; ++kw) {
                float xv = xb[(kd * 96 + kh) * 96 + kw];
                float4 wv = f4load(k + ((kd * 3 + kh) * 3 + kw) * 32 + co4 * 4);
                acc.x += xv * wv.x; acc.y += xv * wv.y;
                acc.z += xv * wv.z; acc.w += xv * wv.w;
            }

    int c0 = co4 * 4;
    float4 gv = f4load(g + c0), bev = f4load(be + c0);
    float4 mv = f4load(m + c0), vv = f4load(v + c0), bv = f4load(b + c0);
    float s;
    ushort4 out;
    s = gv.x * rsqrtf(vv.x + BN_EPS); out.x = f2bf(fmaxf((acc.x + bv.x - mv.x) * s + bev.x, 0.f));
    s = gv.y * rsqrtf(vv.y + BN_EPS); out.y = f2bf(fmaxf((acc.y + bv.y - mv.y) * s + bev.y, 0.f));
    s = gv.z * rsqrtf(vv.z + BN_EPS); out.z = f2bf(fmaxf((acc.z + bv.z - mv.z) * s + bev.z, 0.f));
    s = gv.w * rsqrtf(vv.w + BN_EPS); out.w = f2bf(fmaxf((acc.w + bv.w - mv.w) * s + bev.w, 0.f));

    unsigned short* yp = y + (((size_t)(n * 48 + od) * 48 + oh) * 48 + ow) * 32 + c0;
    *reinterpret_cast<ushort4*>(yp) = out;
}

// ---------------- MFMA implicit-GEMM conv: CIN->COUT, INS^3 -> OUTS^3, stride 2
// A: activations (bf16 NDHWC), fragments gathered directly from global (L1/L2).
// B: pre-transposed weights Wt[tap][cout][cin] bf16, loaded directly from global.
// Wave computes MSUBS... each wave: 1 M-subtile (16 voxels) x NSW N-subtiles (16 couts).
// Block = 4 waves: (4/NH) M-subs x NH cout-halves.
template<int CIN, int COUT, int INS, int OUTS, int NSW>
__global__ __launch_bounds__(256) void conv_mfma(
    const unsigned short* __restrict__ x, const unsigned short* __restrict__ wt,
    const float* __restrict__ b, const float* __restrict__ g,
    const float* __restrict__ be, const float* __restrict__ m,
    const float* __restrict__ v, unsigned short* __restrict__ y)
{
    constexpr int NS = COUT / 16;       // total N-subtiles
    constexpr int NH = NS / NSW;        // cout-groups per block
    constexpr int MSUBS = 4 / NH;       // M-subtiles per block
    constexpr int KS = CIN / 32;        // K-steps per tap
    static_assert(NS % NSW == 0 && 4 % NH == 0, "tiling");

    const int l   = threadIdx.x & 63;
    const int wid = threadIdx.x >> 6;
    const int sg  = l >> 4;             // k-slice group 0..3
    const int lr  = l & 15;

    const int msub = wid / NH;
    const int coutBase = (wid % NH) * NSW * 16;
    const int vbase = blockIdx.x * (16 * MSUBS) + msub * 16;

    // A-fragment row voxel (row = lr)
    int vA = vbase + lr;
    int owA = vA % OUTS; int t1 = vA / OUTS;
    int ohA = t1 % OUTS; int t2 = t1 / OUTS;
    int odA = t2 % OUTS; int nA = t2 / OUTS;
    const unsigned short* ap0 =
        x + ((((size_t)nA * INS + 2 * odA) * INS + 2 * ohA) * INS + 2 * owA) * CIN + sg * 8;
    const bool dE = (odA == OUTS - 1), hE = (ohA == OUTS - 1), wE = (owA == OUTS - 1);

    // B base: col = lr (cout within subtile), k-slice = sg
    const unsigned short* bp0 = wt + ((size_t)coutBase + lr) * CIN + sg * 8;

    f32x4 acc[NSW];
    #pragma unroll
    for (int ns = 0; ns < NSW; ++ns) acc[ns] = (f32x4){0.f, 0.f, 0.f, 0.f};

    #pragma unroll 1
    for (int kd = 0; kd < 3; ++kd) {
        const bool dskip = (kd == 2) && dE;
        #pragma unroll
        for (int kh = 0; kh < 3; ++kh) {
            const bool hskip = dskip || ((kh == 2) && hE);
            #pragma unroll
            for (int kw = 0; kw < 3; ++kw) {
                const bool skip = hskip || ((kw == 2) && wE);
                const int tap = (kd * 3 + kh) * 3 + kw;
                const unsigned short* ap = ap0 + (size_t)((kd * INS + kh) * INS + kw) * CIN;
                const unsigned short* bp = bp0 + (size_t)tap * COUT * CIN;
                #pragma unroll
                for (int ks = 0; ks < KS; ++ks) {
                    short8v a = {0, 0, 0, 0, 0, 0, 0, 0};
                    if (!skip) a = *reinterpret_cast<const short8v*>(ap + ks * 32);
                    #pragma unroll
                    for (int ns = 0; ns < NSW; ++ns) {
                        short8v bf = *reinterpret_cast<const short8v*>(bp + (size_t)ns * 16 * CIN + ks * 32);
                        acc[ns] = __builtin_amdgcn_mfma_f32_16x16x32_bf16(a, bf, acc[ns], 0, 0, 0);
                    }
                }
            }
        }
    }

    // Epilogue: BN + ReLU + bf16 store.
    // D mapping: col = lr (cout), row = sg*4 + i (voxel within M-subtile).
    float S[NSW], T[NSW];
    #pragma unroll
    for (int ns = 0; ns < NSW; ++ns) {
        int c = coutBase + ns * 16 + lr;
        float sc = g[c] * rsqrtf(v[c] + BN_EPS);
        S[ns] = sc;
        T[ns] = (b[c] - m[c]) * sc + be[c];
    }
    #pragma unroll
    for (int i = 0; i < 4; ++i) {
        int vD = vbase + sg * 4 + i;
        int ow = vD % OUTS; int u1 = vD / OUTS;
        int oh = u1 % OUTS; int u2 = u1 / OUTS;
        int od = u2 % OUTS; int n = u2 / OUTS;
        unsigned short* yp =
            y + ((((size_t)n * OUTS + od) * OUTS + oh) * OUTS + ow) * COUT + coutBase + lr;
        #pragma unroll
        for (int ns = 0; ns < NSW; ++ns) {
            float val = fmaxf(acc[ns][i] * S[ns] + T[ns], 0.f);
            yp[ns * 16] = f2bf(val);
        }
    }
}

// ---------------- Head: mean pool + 1x1 conv + BN/ReLU + 1x1 conv + top2 softmax
__global__ __launch_bounds__(256) void head_kernel(
    const unsigned short* __restrict__ x4,   // (16, 6,6,6, 256) bf16
    const float* __restrict__ w1k, const float* __restrict__ w1b,
    const float* __restrict__ wg,  const float* __restrict__ wbe,
    const float* __restrict__ wm,  const float* __restrict__ wv,
    const float* __restrict__ w2k, const float* __restrict__ w2b,
    float* __restrict__ out)
{
    __shared__ float h[256];
    __shared__ float r[256];
    __shared__ float logits[8];

    int n = blockIdx.x;
    int c = threadIdx.x;

    float s = 0.f;
    const unsigned short* xp = x4 + (size_t)n * 216 * 256 + c;
    for (int i = 0; i < 216; ++i) s += bf2f(xp[(size_t)i * 256]);
    h[c] = s * (1.0f / 216.0f);
    __syncthreads();

    float a = w1b[c];
    #pragma unroll 4
    for (int ci = 0; ci < 256; ++ci) a += h[ci] * w1k[ci * 256 + c];
    float sc = wg[c] * rsqrtf(wv[c] + BN_EPS);
    a = (a - wm[c]) * sc + wbe[c];
    r[c] = fmaxf(a, 0.f);
    __syncthreads();

    if (c < 8) {
        float a2 = w2b[c];
        for (int ci = 0; ci < 256; ++ci) a2 += r[ci] * w2k[ci * 8 + c];
        logits[c] = a2;
    }
    __syncthreads();

    if (c == 0) {
        float m1 = -INFINITY, m2 = -INFINITY;
        for (int e = 0; e < 8; ++e) {
            float val = logits[e];
            if (val > m1) { m2 = m1; m1 = val; }
            else if (val > m2) { m2 = val; }
        }
        float thr = m2;
        float ex[8]; float sum = 0.f;
        for (int e = 0; e < 8; ++e) {
            float val = (logits[e] >= thr) ? logits[e] : -INFINITY;
            ex[e] = expf(val - m1);
            sum += ex[e];
        }
        float inv = 1.0f / sum;
        for (int e = 0; e < 8; ++e) out[n * 8 + e] = ex[e] * inv;
    }
}

extern "C" void kernel_launch(void* const* d_in, const int* in_sizes, int n_in,
                              void* d_out, int out_size, void* d_ws, size_t ws_size,
                              hipStream_t stream) {
    const float* x   = (const float*)d_in[0];
    const float* k0  = (const float*)d_in[1];
    const float* b0  = (const float*)d_in[2];
    const float* g0  = (const float*)d_in[3];
    const float* be0 = (const float*)d_in[4];
    const float* m0  = (const float*)d_in[5];
    const float* v0  = (const float*)d_in[6];
    const float* k1  = (const float*)d_in[7];
    const float* b1  = (const float*)d_in[8];
    const float* g1  = (const float*)d_in[9];
    const float* be1 = (const float*)d_in[10];
    const float* m1  = (const float*)d_in[11];
    const float* v1  = (const float*)d_in[12];
    const float* k2  = (const float*)d_in[13];
    const float* b2  = (const float*)d_in[14];
    const float* g2  = (const float*)d_in[15];
    const float* be2 = (const float*)d_in[16];
    const float* m2  = (const float*)d_in[17];
    const float* v2  = (const float*)d_in[18];
    const float* k3  = (const float*)d_in[19];
    const float* b3  = (const float*)d_in[20];
    const float* g3  = (const float*)d_in[21];
    const float* be3 = (const float*)d_in[22];
    const float* m3  = (const float*)d_in[23];
    const float* v3  = (const float*)d_in[24];
    const float* w1k = (const float*)d_in[25];
    const float* w1b = (const float*)d_in[26];
    const float* wg  = (const float*)d_in[27];
    const float* wbe = (const float*)d_in[28];
    const float* wm  = (const float*)d_in[29];
    const float* wv  = (const float*)d_in[30];
    const float* w2k = (const float*)d_in[31];
    const float* w2b = (const float*)d_in[32];

    // workspace (bf16 elems):
    //   x1 56,623,104 | x2 14,155,776 | x3 3,538,944 | x4 884,736
    //   Wt1 55,296 | Wt2 221,184 | Wt3 884,736   -> total ~152.7 MB
    unsigned short* x1  = (unsigned short*)d_ws;
    unsigned short* x2  = x1 + 56623104;
    unsigned short* x3  = x2 + 14155776;
    unsigned short* x4  = x3 + 3538944;
    unsigned short* Wt1 = x4 + 884736;
    unsigned short* Wt2 = Wt1 + 55296;
    unsigned short* Wt3 = Wt2 + 221184;

    wprep_kernel<32, 64><<<27, 256, 0, stream>>>(k1, Wt1);
    wprep_kernel<64, 128><<<108, 256, 0, stream>>>(k2, Wt2);
    wprep_kernel<128, 256><<<432, 256, 0, stream>>>(k3, Wt3);

    conv0_kernel<<<55296, 256, 0, stream>>>(x, k0, b0, g0, be0, m0, v0, x1);
    conv_mfma<32, 64, 48, 24, 4><<<3456, 256, 0, stream>>>(x1, Wt1, b1, g1, be1, m1, v1, x2);
    conv_mfma<64, 128, 24, 12, 8><<<432, 256, 0, stream>>>(x2, Wt2, b2, g2, be2, m2, v2, x3);
    conv_mfma<128, 256, 12, 6, 8><<<108, 256, 0, stream>>>(x3, Wt3, b3, g3, be3, m3, v3, x4);
    head_kernel<<<16, 256, 0, stream>>>(x4, w1k, w1b, wg, wbe, wm, wv, w2k, w2b, (float*)d_out);
}

// Round 4
// 336.737 us; speedup vs baseline: 8.5652x; 2.0680x over previous
//
#include <hip/hip_runtime.h>
#include <math.h>

#define BN_EPS 1e-3f

typedef __attribute__((ext_vector_type(8))) unsigned short ushort8v;
typedef __attribute__((ext_vector_type(8))) short short8v;
typedef __attribute__((ext_vector_type(4))) float f32x4;

__device__ __forceinline__ float4 f4load(const float* p) {
    return *reinterpret_cast<const float4*>(p);
}
__device__ __forceinline__ float bf2f(unsigned short u) {
    union { unsigned int i; float f; } w; w.i = ((unsigned int)u) << 16; return w.f;
}
__device__ __forceinline__ unsigned short f2bf(float f) {
    union { float fv; unsigned int i; } w; w.fv = f;
    unsigned int lsb = (w.i >> 16) & 1u;
    w.i += 0x7fffu + lsb;             // round-to-nearest-even
    return (unsigned short)(w.i >> 16);
}

// ---------------- Weight prep: k[tap][cin][cout] f32 -> Wt[tap][cout][cin] bf16
template<int CIN, int COUT>
__global__ __launch_bounds__(256) void wprep_kernel(
    const float* __restrict__ k, unsigned short* __restrict__ wt)
{
    int idx = blockIdx.x * 256 + threadIdx.x;
    constexpr int CI8 = CIN / 8;
    if (idx >= 27 * COUT * CI8) return;
    int ci0 = (idx % CI8) * 8;
    int c   = (idx / CI8) % COUT;
    int t   = idx / (CI8 * COUT);
    ushort8v o;
    #pragma unroll
    for (int j = 0; j < 8; ++j)
        o[j] = f2bf(k[(size_t)(t * CIN + ci0 + j) * COUT + c]);
    *reinterpret_cast<ushort8v*>(wt + ((size_t)t * COUT + c) * CIN + ci0) = o;
}

// ---------------- Block 0: cin=1, cout=32, 96^3 -> 48^3 (fp32 in, bf16 out)
// Thread = 4 consecutive ow voxels x 8 couts. Input row of 9 floats shared
// across the 4 voxels' taps; weights L1-hot.
__global__ __launch_bounds__(256) void conv0_v2(
    const float* __restrict__ x, const float* __restrict__ k,
    const float* __restrict__ b, const float* __restrict__ g,
    const float* __restrict__ be, const float* __restrict__ m,
    const float* __restrict__ v, unsigned short* __restrict__ y)
{
    int tid = blockIdx.x * 256 + threadIdx.x;
    int co8 = tid & 3;
    int sp  = tid >> 2;
    int owq = sp % 12; sp /= 12;
    int oh  = sp % 48; sp /= 48;
    int od  = sp % 48; int n = sp / 48;   // grid exact: no bounds check
    int c0 = co8 * 8;

    float acc[4][8];
    #pragma unroll
    for (int q = 0; q < 4; ++q)
        #pragma unroll
        for (int j = 0; j < 8; ++j) acc[q][j] = 0.f;

    const int id0 = od * 2, ih0 = oh * 2, iwb = owq * 8;
    const bool wEdge = (owq == 11);

    #pragma unroll 1
    for (int kd = 0; kd < 3; ++kd) {
        int id = id0 + kd; bool dok = id < 96;
        #pragma unroll
        for (int kh = 0; kh < 3; ++kh) {
            int ih = ih0 + kh; bool rok = dok && (ih < 96);
            const float* xr = x + ((size_t)(n * 96 + (rok ? id : 0)) * 96 + (rok ? ih : 0)) * 96 + iwb;
            float4 rA = f4load(xr);
            float4 rB = f4load(xr + 4);
            float r8 = xr[wEdge ? 7 : 8];          // always in-bounds
            float r[9] = {rA.x, rA.y, rA.z, rA.w, rB.x, rB.y, rB.z, rB.w, r8};
            if (wEdge) r[8] = 0.f;
            if (!rok) {
                #pragma unroll
                for (int j = 0; j < 9; ++j) r[j] = 0.f;
            }
            #pragma unroll
            for (int kw = 0; kw < 3; ++kw) {
                const float* wp = k + ((kd * 3 + kh) * 3 + kw) * 32 + c0;
                float4 wA = f4load(wp), wB = f4load(wp + 4);
                float w8[8] = {wA.x, wA.y, wA.z, wA.w, wB.x, wB.y, wB.z, wB.w};
                #pragma unroll
                for (int q = 0; q < 4; ++q) {
                    float xv = r[2 * q + kw];
                    #pragma unroll
                    for (int j = 0; j < 8; ++j) acc[q][j] += xv * w8[j];
                }
            }
        }
    }

    float S[8], T[8];
    #pragma unroll
    for (int j = 0; j < 8; ++j) {
        int c = c0 + j;
        float sc = g[c] * rsqrtf(v[c] + BN_EPS);
        S[j] = sc;
        T[j] = (b[c] - m[c]) * sc + be[c];
    }
    #pragma unroll
    for (int q = 0; q < 4; ++q) {
        int ow = owq * 4 + q;
        unsigned short* yp = y + (((size_t)(n * 48 + od) * 48 + oh) * 48 + ow) * 32 + c0;
        ushort8v o;
        #pragma unroll
        for (int j = 0; j < 8; ++j)
            o[j] = f2bf(fmaxf(acc[q][j] * S[j] + T[j], 0.f));
        *reinterpret_cast<ushort8v*>(yp) = o;
    }
}

// ---------------- MFMA implicit-GEMM conv, register-blocked.
// Wave: MW M-subtiles (16 voxels each) x NSW N-subtiles (16 couts each).
// Block: 4 waves = (4/NH) M-groups x NH cout-groups.
template<int CIN, int COUT, int INS, int OUTS, int MW, int NSW, int NH>
__global__ __launch_bounds__(256) void conv_mfma(
    const unsigned short* __restrict__ x, const unsigned short* __restrict__ wt,
    const float* __restrict__ b, const float* __restrict__ g,
    const float* __restrict__ be, const float* __restrict__ m,
    const float* __restrict__ v, unsigned short* __restrict__ y)
{
    constexpr int NS = COUT / 16;
    constexpr int KS = CIN / 32;
    constexpr int MGROUPS = 4 / NH;
    constexpr int MTILE = MGROUPS * MW * 16;
    static_assert(NS == NSW * NH && 4 % NH == 0, "tiling");

    const int l   = threadIdx.x & 63;
    const int wid = threadIdx.x >> 6;
    const int sg  = l >> 4;
    const int lr  = l & 15;

    const int mgroup = wid / NH;
    const int ngroup = wid % NH;
    const int coutBase = ngroup * NSW * 16;
    const int vwave = blockIdx.x * MTILE + mgroup * MW * 16;

    const unsigned short* ap0[MW];
    bool dE[MW], hE[MW], wE[MW];
    #pragma unroll
    for (int mi = 0; mi < MW; ++mi) {
        int vA = vwave + mi * 16 + lr;
        int owA = vA % OUTS; int t1 = vA / OUTS;
        int ohA = t1 % OUTS; int t2 = t1 / OUTS;
        int odA = t2 % OUTS; int nA = t2 / OUTS;
        ap0[mi] = x + ((((size_t)nA * INS + 2 * odA) * INS + 2 * ohA) * INS + 2 * owA) * CIN + sg * 8;
        dE[mi] = (odA == OUTS - 1); hE[mi] = (ohA == OUTS - 1); wE[mi] = (owA == OUTS - 1);
    }

    const unsigned short* bp0 = wt + ((size_t)coutBase + lr) * CIN + sg * 8;

    f32x4 acc[MW][NSW];
    #pragma unroll
    for (int mi = 0; mi < MW; ++mi)
        #pragma unroll
        for (int ns = 0; ns < NSW; ++ns) acc[mi][ns] = (f32x4){0.f, 0.f, 0.f, 0.f};

    #pragma unroll 1
    for (int kd = 0; kd < 3; ++kd) {
        #pragma unroll
        for (int kh = 0; kh < 3; ++kh) {
            #pragma unroll
            for (int kw = 0; kw < 3; ++kw) {
                const int tap = (kd * 3 + kh) * 3 + kw;
                const size_t aoff = (size_t)((kd * INS + kh) * INS + kw) * CIN;
                const unsigned short* bp = bp0 + (size_t)tap * COUT * CIN;
                #pragma unroll
                for (int ks = 0; ks < KS; ++ks) {
                    short8v a[MW], bf[NSW];
                    #pragma unroll
                    for (int mi = 0; mi < MW; ++mi) {
                        bool skip = ((kd == 2) && dE[mi]) || ((kh == 2) && hE[mi]) || ((kw == 2) && wE[mi]);
                        short8v t = {0, 0, 0, 0, 0, 0, 0, 0};
                        if (!skip) t = *reinterpret_cast<const short8v*>(ap0[mi] + aoff + ks * 32);
                        a[mi] = t;
                    }
                    #pragma unroll
                    for (int ns = 0; ns < NSW; ++ns)
                        bf[ns] = *reinterpret_cast<const short8v*>(bp + (size_t)ns * 16 * CIN + ks * 32);
                    #pragma unroll
                    for (int mi = 0; mi < MW; ++mi)
                        #pragma unroll
                        for (int ns = 0; ns < NSW; ++ns)
                            acc[mi][ns] = __builtin_amdgcn_mfma_f32_16x16x32_bf16(a[mi], bf[ns], acc[mi][ns], 0, 0, 0);
                }
            }
        }
    }

    float S[NSW], T[NSW];
    #pragma unroll
    for (int ns = 0; ns < NSW; ++ns) {
        int c = coutBase + ns * 16 + lr;
        float sc = g[c] * rsqrtf(v[c] + BN_EPS);
        S[ns] = sc;
        T[ns] = (b[c] - m[c]) * sc + be[c];
    }
    #pragma unroll
    for (int mi = 0; mi < MW; ++mi) {
        #pragma unroll
        for (int i = 0; i < 4; ++i) {
            int vD = vwave + mi * 16 + sg * 4 + i;
            int ow = vD % OUTS; int u1 = vD / OUTS;
            int oh = u1 % OUTS; int u2 = u1 / OUTS;
            int od = u2 % OUTS; int n = u2 / OUTS;
            unsigned short* yp =
                y + ((((size_t)n * OUTS + od) * OUTS + oh) * OUTS + ow) * COUT + coutBase + lr;
            #pragma unroll
            for (int ns = 0; ns < NSW; ++ns)
                yp[ns * 16] = f2bf(fmaxf(acc[mi][ns][i] * S[ns] + T[ns], 0.f));
        }
    }
}

// ---------------- Head: mean pool + 1x1 conv + BN/ReLU + 1x1 conv + top2 softmax
__global__ __launch_bounds__(256) void head_kernel(
    const unsigned short* __restrict__ x4,   // (16, 6,6,6, 256) bf16
    const float* __restrict__ w1k, const float* __restrict__ w1b,
    const float* __restrict__ wg,  const float* __restrict__ wbe,
    const float* __restrict__ wm,  const float* __restrict__ wv,
    const float* __restrict__ w2k, const float* __restrict__ w2b,
    float* __restrict__ out)
{
    __shared__ float h[256];
    __shared__ float r[256];
    __shared__ float logits[8];

    int n = blockIdx.x;
    int c = threadIdx.x;

    float s = 0.f;
    const unsigned short* xp = x4 + (size_t)n * 216 * 256 + c;
    for (int i = 0; i < 216; ++i) s += bf2f(xp[(size_t)i * 256]);
    h[c] = s * (1.0f / 216.0f);
    __syncthreads();

    float a = w1b[c];
    #pragma unroll 4
    for (int ci = 0; ci < 256; ++ci) a += h[ci] * w1k[ci * 256 + c];
    float sc = wg[c] * rsqrtf(wv[c] + BN_EPS);
    a = (a - wm[c]) * sc + wbe[c];
    r[c] = fmaxf(a, 0.f);
    __syncthreads();

    if (c < 8) {
        float a2 = w2b[c];
        for (int ci = 0; ci < 256; ++ci) a2 += r[ci] * w2k[ci * 8 + c];
        logits[c] = a2;
    }
    __syncthreads();

    if (c == 0) {
        float m1 = -INFINITY, m2 = -INFINITY;
        for (int e = 0; e < 8; ++e) {
            float val = logits[e];
            if (val > m1) { m2 = m1; m1 = val; }
            else if (val > m2) { m2 = val; }
        }
        float thr = m2;
        float ex[8]; float sum = 0.f;
        for (int e = 0; e < 8; ++e) {
            float val = (logits[e] >= thr) ? logits[e] : -INFINITY;
            ex[e] = expf(val - m1);
            sum += ex[e];
        }
        float inv = 1.0f / sum;
        for (int e = 0; e < 8; ++e) out[n * 8 + e] = ex[e] * inv;
    }
}

extern "C" void kernel_launch(void* const* d_in, const int* in_sizes, int n_in,
                              void* d_out, int out_size, void* d_ws, size_t ws_size,
                              hipStream_t stream) {
    const float* x   = (const float*)d_in[0];
    const float* k0  = (const float*)d_in[1];
    const float* b0  = (const float*)d_in[2];
    const float* g0  = (const float*)d_in[3];
    const float* be0 = (const float*)d_in[4];
    const float* m0  = (const float*)d_in[5];
    const float* v0  = (const float*)d_in[6];
    const float* k1  = (const float*)d_in[7];
    const float* b1  = (const float*)d_in[8];
    const float* g1  = (const float*)d_in[9];
    const float* be1 = (const float*)d_in[10];
    const float* m1  = (const float*)d_in[11];
    const float* v1  = (const float*)d_in[12];
    const float* k2  = (const float*)d_in[13];
    const float* b2  = (const float*)d_in[14];
    const float* g2  = (const float*)d_in[15];
    const float* be2 = (const float*)d_in[16];
    const float* m2  = (const float*)d_in[17];
    const float* v2  = (const float*)d_in[18];
    const float* k3  = (const float*)d_in[19];
    const float* b3  = (const float*)d_in[20];
    const float* g3  = (const float*)d_in[21];
    const float* be3 = (const float*)d_in[22];
    const float* m3  = (const float*)d_in[23];
    const float* v3  = (const float*)d_in[24];
    const float* w1k = (const float*)d_in[25];
    const float* w1b = (const float*)d_in[26];
    const float* wg  = (const float*)d_in[27];
    const float* wbe = (const float*)d_in[28];
    const float* wm  = (const float*)d_in[29];
    const float* wv  = (const float*)d_in[30];
    const float* w2k = (const float*)d_in[31];
    const float* w2b = (const float*)d_in[32];

    unsigned short* x1  = (unsigned short*)d_ws;
    unsigned short* x2  = x1 + 56623104;
    unsigned short* x3  = x2 + 14155776;
    unsigned short* x4  = x3 + 3538944;
    unsigned short* Wt1 = x4 + 884736;
    unsigned short* Wt2 = Wt1 + 55296;
    unsigned short* Wt3 = Wt2 + 221184;

    wprep_kernel<32, 64><<<27, 256, 0, stream>>>(k1, Wt1);
    wprep_kernel<64, 128><<<108, 256, 0, stream>>>(k2, Wt2);
    wprep_kernel<128, 256><<<432, 256, 0, stream>>>(k3, Wt3);

    conv0_v2<<<6912, 256, 0, stream>>>(x, k0, b0, g0, be0, m0, v0, x1);
    conv_mfma<32, 64, 48, 24, 4, 4, 1><<<864, 256, 0, stream>>>(x1, Wt1, b1, g1, be1, m1, v1, x2);
    conv_mfma<64, 128, 24, 12, 4, 4, 2><<<216, 256, 0, stream>>>(x2, Wt2, b2, g2, be2, m2, v2, x3);
    conv_mfma<128, 256, 12, 6, 2, 4, 4><<<108, 256, 0, stream>>>(x3, Wt3, b3, g3, be3, m3, v3, x4);
    head_kernel<<<16, 256, 0, stream>>>(x4, w1k, w1b, wg, wbe, wm, wv, w2k, w2b, (float*)d_out);
}

// Round 5
// 328.604 us; speedup vs baseline: 8.7772x; 1.0248x over previous
//
#include <hip/hip_runtime.h>
#include <math.h>

#define BN_EPS 1e-3f

typedef __attribute__((ext_vector_type(8))) unsigned short ushort8v;
typedef __attribute__((ext_vector_type(8))) short short8v;
typedef __attribute__((ext_vector_type(4))) float f32x4;

__device__ __forceinline__ float4 f4load(const float* p) {
    return *reinterpret_cast<const float4*>(p);
}
__device__ __forceinline__ float bf2f(unsigned short u) {
    union { unsigned int i; float f; } w; w.i = ((unsigned int)u) << 16; return w.f;
}
__device__ __forceinline__ unsigned short f2bf(float f) {
    union { float fv; unsigned int i; } w; w.fv = f;
    unsigned int lsb = (w.i >> 16) & 1u;
    w.i += 0x7fffu + lsb;             // round-to-nearest-even
    return (unsigned short)(w.i >> 16);
}

// ---------------- Weight prep: k[tap][cin][cout] f32 -> Wt[tap][cout][cin] bf16
template<int CIN, int COUT>
__device__ __forceinline__ void wprep_body(
    const float* __restrict__ k, unsigned short* __restrict__ wt, int blk)
{
    int idx = blk * 256 + (int)threadIdx.x;
    constexpr int CI8 = CIN / 8;
    if (idx >= 27 * COUT * CI8) return;
    int ci0 = (idx % CI8) * 8;
    int c   = (idx / CI8) % COUT;
    int t   = idx / (CI8 * COUT);
    ushort8v o;
    #pragma unroll
    for (int j = 0; j < 8; ++j)
        o[j] = f2bf(k[(size_t)(t * CIN + ci0 + j) * COUT + c]);
    *reinterpret_cast<ushort8v*>(wt + ((size_t)t * COUT + c) * CIN + ci0) = o;
}

__global__ __launch_bounds__(256) void wprep_all(
    const float* __restrict__ k1, const float* __restrict__ k2, const float* __restrict__ k3,
    unsigned short* __restrict__ w1, unsigned short* __restrict__ w2, unsigned short* __restrict__ w3)
{
    int b = blockIdx.x;
    if (b < 27)       wprep_body<32, 64>(k1, w1, b);
    else if (b < 135) wprep_body<64, 128>(k2, w2, b - 27);
    else              wprep_body<128, 256>(k3, w3, b - 135);
}

// ---------------- Block 0: cin=1, cout=32, 96^3 -> 48^3 (fp32 in, bf16 out)
// Thread = 8 consecutive ow voxels x 8 couts. 17-float input row shared
// across the 8 voxels' taps; weights L1-hot.
__global__ __launch_bounds__(256) void conv0_v3(
    const float* __restrict__ x, const float* __restrict__ k,
    const float* __restrict__ b, const float* __restrict__ g,
    const float* __restrict__ be, const float* __restrict__ m,
    const float* __restrict__ v, unsigned short* __restrict__ y)
{
    int t = blockIdx.x * 256 + threadIdx.x;
    int co8 = t & 3;  t >>= 2;
    int owq = t % 6;  t /= 6;
    int oh  = t % 48; t /= 48;
    int od  = t % 48; int n = t / 48;    // grid exact
    const int c0 = co8 * 8;

    float acc[8][8];
    #pragma unroll
    for (int q = 0; q < 8; ++q)
        #pragma unroll
        for (int j = 0; j < 8; ++j) acc[q][j] = 0.f;

    const int id0 = od * 2, ih0 = oh * 2, iwb = owq * 16;
    const bool wEdge = (owq == 5);

    #pragma unroll 1
    for (int kd = 0; kd < 3; ++kd) {
        int id = id0 + kd; bool dok = id < 96;
        #pragma unroll
        for (int kh = 0; kh < 3; ++kh) {
            int ih = ih0 + kh; bool rok = dok && (ih < 96);
            const float* xr = x + ((size_t)(n * 96 + (rok ? id : 0)) * 96 + (rok ? ih : 0)) * 96 + iwb;
            float4 rA = f4load(xr);
            float4 rB = f4load(xr + 4);
            float4 rC = f4load(xr + 8);
            float4 rD = f4load(xr + 12);
            float r16 = xr[wEdge ? 15 : 16];
            float r[17] = {rA.x, rA.y, rA.z, rA.w, rB.x, rB.y, rB.z, rB.w,
                           rC.x, rC.y, rC.z, rC.w, rD.x, rD.y, rD.z, rD.w, r16};
            if (wEdge) r[16] = 0.f;
            if (!rok) {
                #pragma unroll
                for (int j = 0; j < 17; ++j) r[j] = 0.f;
            }
            #pragma unroll
            for (int kw = 0; kw < 3; ++kw) {
                const float* wp = k + ((kd * 3 + kh) * 3 + kw) * 32 + c0;
                float4 wA = f4load(wp), wB = f4load(wp + 4);
                float w8[8] = {wA.x, wA.y, wA.z, wA.w, wB.x, wB.y, wB.z, wB.w};
                #pragma unroll
                for (int q = 0; q < 8; ++q) {
                    float xv = r[2 * q + kw];
                    #pragma unroll
                    for (int j = 0; j < 8; ++j) acc[q][j] += xv * w8[j];
                }
            }
        }
    }

    float S[8], T[8];
    #pragma unroll
    for (int j = 0; j < 8; ++j) {
        int c = c0 + j;
        float sc = g[c] * rsqrtf(v[c] + BN_EPS);
        S[j] = sc;
        T[j] = (b[c] - m[c]) * sc + be[c];
    }
    #pragma unroll
    for (int q = 0; q < 8; ++q) {
        int ow = owq * 8 + q;
        unsigned short* yp = y + (((size_t)(n * 48 + od) * 48 + oh) * 48 + ow) * 32 + c0;
        ushort8v o;
        #pragma unroll
        for (int j = 0; j < 8; ++j)
            o[j] = f2bf(fmaxf(acc[q][j] * S[j] + T[j], 0.f));
        *reinterpret_cast<ushort8v*>(yp) = o;
    }
}

// ---------------- MFMA implicit-GEMM conv, register-blocked.
// Wave: MW M-subtiles (16 voxels each) x NSW N-subtiles (16 couts each).
// Block: 4 waves = (4/NH) M-groups x NH cout-groups.
template<int CIN, int COUT, int INS, int OUTS, int MW, int NSW, int NH>
__global__ __launch_bounds__(256) void conv_mfma(
    const unsigned short* __restrict__ x, const unsigned short* __restrict__ wt,
    const float* __restrict__ b, const float* __restrict__ g,
    const float* __restrict__ be, const float* __restrict__ m,
    const float* __restrict__ v, unsigned short* __restrict__ y)
{
    constexpr int NS = COUT / 16;
    constexpr int KS = CIN / 32;
    constexpr int MGROUPS = 4 / NH;
    constexpr int MTILE = MGROUPS * MW * 16;
    static_assert(NS == NSW * NH && 4 % NH == 0, "tiling");

    const int l   = threadIdx.x & 63;
    const int wid = threadIdx.x >> 6;
    const int sg  = l >> 4;
    const int lr  = l & 15;

    const int mgroup = wid / NH;
    const int ngroup = wid % NH;
    const int coutBase = ngroup * NSW * 16;
    const int vwave = blockIdx.x * MTILE + mgroup * MW * 16;

    const unsigned short* ap0[MW];
    bool dE[MW], hE[MW], wE[MW];
    #pragma unroll
    for (int mi = 0; mi < MW; ++mi) {
        int vA = vwave + mi * 16 + lr;
        int owA = vA % OUTS; int t1 = vA / OUTS;
        int ohA = t1 % OUTS; int t2 = t1 / OUTS;
        int odA = t2 % OUTS; int nA = t2 / OUTS;
        ap0[mi] = x + ((((size_t)nA * INS + 2 * odA) * INS + 2 * ohA) * INS + 2 * owA) * CIN + sg * 8;
        dE[mi] = (odA == OUTS - 1); hE[mi] = (ohA == OUTS - 1); wE[mi] = (owA == OUTS - 1);
    }

    const unsigned short* bp0 = wt + ((size_t)coutBase + lr) * CIN + sg * 8;

    f32x4 acc[MW][NSW];
    #pragma unroll
    for (int mi = 0; mi < MW; ++mi)
        #pragma unroll
        for (int ns = 0; ns < NSW; ++ns) acc[mi][ns] = (f32x4){0.f, 0.f, 0.f, 0.f};

    #pragma unroll 1
    for (int kd = 0; kd < 3; ++kd) {
        #pragma unroll
        for (int kh = 0; kh < 3; ++kh) {
            #pragma unroll
            for (int kw = 0; kw < 3; ++kw) {
                const int tap = (kd * 3 + kh) * 3 + kw;
                const size_t aoff = (size_t)((kd * INS + kh) * INS + kw) * CIN;
                const unsigned short* bp = bp0 + (size_t)tap * COUT * CIN;
                #pragma unroll
                for (int ks = 0; ks < KS; ++ks) {
                    short8v a[MW], bf[NSW];
                    #pragma unroll
                    for (int mi = 0; mi < MW; ++mi) {
                        bool skip = ((kd == 2) && dE[mi]) || ((kh == 2) && hE[mi]) || ((kw == 2) && wE[mi]);
                        short8v tv = {0, 0, 0, 0, 0, 0, 0, 0};
                        if (!skip) tv = *reinterpret_cast<const short8v*>(ap0[mi] + aoff + ks * 32);
                        a[mi] = tv;
                    }
                    #pragma unroll
                    for (int ns = 0; ns < NSW; ++ns)
                        bf[ns] = *reinterpret_cast<const short8v*>(bp + (size_t)ns * 16 * CIN + ks * 32);
                    #pragma unroll
                    for (int mi = 0; mi < MW; ++mi)
                        #pragma unroll
                        for (int ns = 0; ns < NSW; ++ns)
                            acc[mi][ns] = __builtin_amdgcn_mfma_f32_16x16x32_bf16(a[mi], bf[ns], acc[mi][ns], 0, 0, 0);
                }
            }
        }
    }

    float S[NSW], T[NSW];
    #pragma unroll
    for (int ns = 0; ns < NSW; ++ns) {
        int c = coutBase + ns * 16 + lr;
        float sc = g[c] * rsqrtf(v[c] + BN_EPS);
        S[ns] = sc;
        T[ns] = (b[c] - m[c]) * sc + be[c];
    }
    #pragma unroll
    for (int mi = 0; mi < MW; ++mi) {
        #pragma unroll
        for (int i = 0; i < 4; ++i) {
            int vD = vwave + mi * 16 + sg * 4 + i;
            int ow = vD % OUTS; int u1 = vD / OUTS;
            int oh = u1 % OUTS; int u2 = u1 / OUTS;
            int od = u2 % OUTS; int n = u2 / OUTS;
            unsigned short* yp =
                y + ((((size_t)n * OUTS + od) * OUTS + oh) * OUTS + ow) * COUT + coutBase + lr;
            #pragma unroll
            for (int ns = 0; ns < NSW; ++ns)
                yp[ns * 16] = f2bf(fmaxf(acc[mi][ns][i] * S[ns] + T[ns], 0.f));
        }
    }
}

// ---------------- Head: mean pool + 1x1 conv + BN/ReLU + 1x1 conv + top2 softmax
__global__ __launch_bounds__(256) void head_kernel(
    const unsigned short* __restrict__ x4,   // (16, 6,6,6, 256) bf16
    const float* __restrict__ w1k, const float* __restrict__ w1b,
    const float* __restrict__ wg,  const float* __restrict__ wbe,
    const float* __restrict__ wm,  const float* __restrict__ wv,
    const float* __restrict__ w2k, const float* __restrict__ w2b,
    float* __restrict__ out)
{
    __shared__ float part[8][256];
    __shared__ float h[256];
    __shared__ float r[256];
    __shared__ float logits[8];

    const int n = blockIdx.x;
    const int t = threadIdx.x;
    const int c8 = t & 31;        // channel-group (8 channels)
    const int pg = t >> 5;        // position group 0..7

    // coalesced mean pool: threads 0..31 of each pg cover a full 256-ch row
    const unsigned short* xb = x4 + (size_t)n * 216 * 256 + c8 * 8;
    float s[8] = {0.f, 0.f, 0.f, 0.f, 0.f, 0.f, 0.f, 0.f};
    for (int i = pg; i < 216; i += 8) {
        ushort8v v8 = *reinterpret_cast<const ushort8v*>(xb + (size_t)i * 256);
        #pragma unroll
        for (int j = 0; j < 8; ++j) s[j] += bf2f(v8[j]);
    }
    #pragma unroll
    for (int j = 0; j < 8; ++j) part[pg][c8 * 8 + j] = s[j];
    __syncthreads();

    float a = 0.f;
    #pragma unroll
    for (int gi = 0; gi < 8; ++gi) a += part[gi][t];
    h[t] = a * (1.0f / 216.0f);
    __syncthreads();

    // w1 (256x256) + BN + ReLU
    float acc = w1b[t];
    #pragma unroll 4
    for (int ci = 0; ci < 256; ++ci) acc += h[ci] * w1k[ci * 256 + t];
    float sc = wg[t] * rsqrtf(wv[t] + BN_EPS);
    acc = (acc - wm[t]) * sc + wbe[t];
    r[t] = fmaxf(acc, 0.f);
    __syncthreads();

    if (t < 8) {
        float a2 = w2b[t];
        for (int ci = 0; ci < 256; ++ci) a2 += r[ci] * w2k[ci * 8 + t];
        logits[t] = a2;
    }
    __syncthreads();

    if (t == 0) {
        float m1 = -INFINITY, m2 = -INFINITY;
        for (int e = 0; e < 8; ++e) {
            float val = logits[e];
            if (val > m1) { m2 = m1; m1 = val; }
            else if (val > m2) { m2 = val; }
        }
        float thr = m2;
        float ex[8]; float sum = 0.f;
        for (int e = 0; e < 8; ++e) {
            float val = (logits[e] >= thr) ? logits[e] : -INFINITY;
            ex[e] = expf(val - m1);
            sum += ex[e];
        }
        float inv = 1.0f / sum;
        for (int e = 0; e < 8; ++e) out[n * 8 + e] = ex[e] * inv;
    }
}

extern "C" void kernel_launch(void* const* d_in, const int* in_sizes, int n_in,
                              void* d_out, int out_size, void* d_ws, size_t ws_size,
                              hipStream_t stream) {
    const float* x   = (const float*)d_in[0];
    const float* k0  = (const float*)d_in[1];
    const float* b0  = (const float*)d_in[2];
    const float* g0  = (const float*)d_in[3];
    const float* be0 = (const float*)d_in[4];
    const float* m0  = (const float*)d_in[5];
    const float* v0  = (const float*)d_in[6];
    const float* k1  = (const float*)d_in[7];
    const float* b1  = (const float*)d_in[8];
    const float* g1  = (const float*)d_in[9];
    const float* be1 = (const float*)d_in[10];
    const float* m1  = (const float*)d_in[11];
    const float* v1  = (const float*)d_in[12];
    const float* k2  = (const float*)d_in[13];
    const float* b2  = (const float*)d_in[14];
    const float* g2  = (const float*)d_in[15];
    const float* be2 = (const float*)d_in[16];
    const float* m2  = (const float*)d_in[17];
    const float* v2  = (const float*)d_in[18];
    const float* k3  = (const float*)d_in[19];
    const float* b3  = (const float*)d_in[20];
    const float* g3  = (const float*)d_in[21];
    const float* be3 = (const float*)d_in[22];
    const float* m3  = (const float*)d_in[23];
    const float* v3  = (const float*)d_in[24];
    const float* w1k = (const float*)d_in[25];
    const float* w1b = (const float*)d_in[26];
    const float* wg  = (const float*)d_in[27];
    const float* wbe = (const float*)d_in[28];
    const float* wm  = (const float*)d_in[29];
    const float* wv  = (const float*)d_in[30];
    const float* w2k = (const float*)d_in[31];
    const float* w2b = (const float*)d_in[32];

    unsigned short* x1  = (unsigned short*)d_ws;
    unsigned short* x2  = x1 + 56623104;
    unsigned short* x3  = x2 + 14155776;
    unsigned short* x4  = x3 + 3538944;
    unsigned short* Wt1 = x4 + 884736;
    unsigned short* Wt2 = Wt1 + 55296;
    unsigned short* Wt3 = Wt2 + 221184;

    wprep_all<<<567, 256, 0, stream>>>(k1, k2, k3, Wt1, Wt2, Wt3);
    conv0_v3<<<3456, 256, 0, stream>>>(x, k0, b0, g0, be0, m0, v0, x1);
    conv_mfma<32, 64, 48, 24, 6, 4, 1><<<576, 256, 0, stream>>>(x1, Wt1, b1, g1, be1, m1, v1, x2);
    conv_mfma<64, 128, 24, 12, 4, 4, 2><<<216, 256, 0, stream>>>(x2, Wt2, b2, g2, be2, m2, v2, x3);
    conv_mfma<128, 256, 12, 6, 2, 4, 4><<<108, 256, 0, stream>>>(x3, Wt3, b3, g3, be3, m3, v3, x4);
    head_kernel<<<16, 256, 0, stream>>>(x4, w1k, w1b, wg, wbe, wm, wv, w2k, w2b, (float*)d_out);
}